// Round 15
// baseline (118.625 us; speedup 1.0000x reference)
//
#include <hip/hip_runtime.h>
#include <stdint.h>

#define NB 4
#define SS 192
#define NI 256

typedef __attribute__((ext_vector_type(8))) short bf16x8;
typedef __attribute__((ext_vector_type(16))) float f32x16;

__device__ __forceinline__ uint16_t f2bf(float f) {
  union { float f; uint32_t u; } v; v.f = f;
  return (uint16_t)((v.u + 0x7FFFu + ((v.u >> 16) & 1u)) >> 16);
}

__device__ __forceinline__ uint4 pack8(const float4 a, const float4 b) {
  uint4 r;
  r.x = (uint32_t)f2bf(a.x) | ((uint32_t)f2bf(a.y) << 16);
  r.y = (uint32_t)f2bf(a.z) | ((uint32_t)f2bf(a.w) << 16);
  r.z = (uint32_t)f2bf(b.x) | ((uint32_t)f2bf(b.y) << 16);
  r.w = (uint32_t)f2bf(b.z) | ((uint32_t)f2bf(b.w) << 16);
  return r;
}

__device__ __forceinline__ uint32_t bfmul2(uint32_t x, uint32_t y) {
  union { float f; uint32_t u; } xa, xb, ya, yb, r0, r1;
  xa.u = x << 16;        ya.u = y << 16;
  xb.u = x & 0xFFFF0000u; yb.u = y & 0xFFFF0000u;
  r0.f = xa.f * ya.f;
  r1.f = xb.f * yb.f;
  uint32_t lo = (r0.u + 0x7FFFu + ((r0.u >> 16) & 1u)) >> 16;
  uint32_t hi = (r1.u + 0x7FFFu + ((r1.u >> 16) & 1u)) >> 16;
  return lo | (hi << 16);
}

// Canonical bf16 storage: row-major, 8-elem chunk c stored at position c ^ (row&15).
// partial[] contract: 2048 chunks of 8192 floats; w_red[i] = sum(partial[8i..8i+7]).

// ---------------- K_A: s1-blocks (0..23) + HH/HS converts (24..119) + W partials (120..2167) ----------------
__global__ __launch_bounds__(256) void kA(
    const float* __restrict__ W,
    const float* __restrict__ h_head, const float* __restrict__ h_dep, const float* __restrict__ h_sib,
    const float* __restrict__ U, const float* __restrict__ V, const float* __restrict__ Z,
    float* __restrict__ partial,
    uint16_t* __restrict__ HH, uint16_t* __restrict__ HS,
    uint16_t* __restrict__ dU16, uint16_t* __restrict__ T216, uint16_t* __restrict__ TZ16) {
  const int bi = blockIdx.x, tid = threadIdx.x;

  if (bi >= 120) {
    // ---- W chunk: sum 8192 consecutive floats ----
    __shared__ float red[4];
    const int c = bi - 120;
    const float4* pw = (const float4*)(W + (size_t)c * 8192);
    float4 a = {0.f, 0.f, 0.f, 0.f};
    #pragma unroll
    for (int it = 0; it < 8; ++it) {
      const float4 v = pw[it * 256 + tid];
      a.x += v.x; a.y += v.y; a.z += v.z; a.w += v.w;
    }
    float s = (a.x + a.y) + (a.z + a.w);
    for (int off = 32; off > 0; off >>= 1) s += __shfl_down(s, off, 64);
    if ((tid & 63) == 0) red[tid >> 6] = s;
    __syncthreads();
    if (tid == 0) partial[c] = red[0] + red[1] + red[2] + red[3];
    return;
  }
  if (bi >= 24) {
    // ---- converts: canonical swizzled bf16 (HH, HS) for K_B ----
    const int rl = tid >> 5, c8 = tid & 31;
    const int g = (bi - 24) * 8 + rl;              // 0..767
    const int dst = g * 32 + (c8 ^ (g & 15));
    const int srci = g * 64 + c8 * 2;
    { const float4 x = ((const float4*)h_head)[srci], y = ((const float4*)h_head)[srci + 1];
      ((uint4*)HH)[dst] = pack8(x, y); }
    { const float4 x = ((const float4*)h_sib)[srci], y = ((const float4*)h_sib)[srci + 1];
      ((uint4*)HS)[dst] = pack8(x, y); }
    return;
  }

  // ---- s1 block: dU/T2/TZ = A(192xK) x B(U/V/Z rows)^T, self-converting staging ----
  {
    __shared__ __align__(16) uint16_t Ah[192 * 128];   // 48 KB
    __shared__ __align__(16) uint16_t Bh[128 * 128];   // 32 KB
    const int which = bi >> 3, rem = bi & 7;
    const int b = rem >> 1, nt = rem & 1;
    const float* As = (which == 0) ? h_dep : h_sib;
    const float* Bs = (which == 0) ? U : (which == 1) ? V : Z;
    uint16_t* Os = (which == 0) ? dU16 : (which == 1) ? T216 : TZ16;
    const int lane = tid & 63, w = tid >> 6;
    const int l31 = lane & 31, l5 = lane >> 5;
    const int N0 = nt * 128;
    f32x16 acc[6] = {};

    #pragma unroll
    for (int kh = 0; kh < 2; ++kh) {
      const int kbase = kh * 128;
      if (kh) __syncthreads();
      // stage A: 192x128 from f32, convert, swizzled ds_write (3072 chunks / 256 thr)
      #pragma unroll
      for (int i = 0; i < 12; ++i) {
        const int slot = i * 256 + tid;
        const int row = slot >> 4, ck = slot & 15;
        const float* sp = As + (size_t)(b * SS + row) * NI + kbase + ck * 8;
        const float4 x = *(const float4*)sp, y = *(const float4*)(sp + 4);
        *(uint4*)((char*)Ah + row * 256 + ((ck ^ (row & 15)) << 4)) = pack8(x, y);
      }
      // stage B: 128x128 from f32 (2048 chunks / 256 thr)
      #pragma unroll
      for (int i = 0; i < 8; ++i) {
        const int slot = i * 256 + tid;
        const int row = slot >> 4, ck = slot & 15;
        const float* sp = Bs + (size_t)(N0 + row) * NI + kbase + ck * 8;
        const float4 x = *(const float4*)sp, y = *(const float4*)(sp + 4);
        *(uint4*)((char*)Bh + row * 256 + ((ck ^ (row & 15)) << 4)) = pack8(x, y);
      }
      __syncthreads();
      const int brow = w * 32 + l31;
      const int bbyte = brow * 256;
      const int bmask = brow & 15;
      #pragma unroll
      for (int ks = 0; ks < 8; ++ks) {
        const int sl = ks * 2 + l5;
        bf16x8 bf = *reinterpret_cast<const bf16x8*>((const char*)Bh + bbyte + ((sl ^ bmask) << 4));
        #pragma unroll
        for (int mt = 0; mt < 6; ++mt) {
          const int ar = mt * 32 + l31;
          bf16x8 af = *reinterpret_cast<const bf16x8*>((const char*)Ah + ar * 256 + ((sl ^ (ar & 15)) << 4));
          acc[mt] = __builtin_amdgcn_mfma_f32_32x32x16_bf16(af, bf, acc[mt], 0, 0, 0);
        }
      }
    }
    const int n = N0 + w * 32 + l31;
    const int nck = n >> 3, npos = n & 7;
    #pragma unroll
    for (int mt = 0; mt < 6; ++mt) {
      #pragma unroll
      for (int r = 0; r < 16; ++r) {
        const int m = mt * 32 + (r & 3) + 8 * (r >> 2) + 4 * l5;
        Os[(size_t)(b * SS + m) * NI + ((nck ^ (m & 15)) << 3) + npos] = f2bf(acc[mt][r]);
      }
    }
  }
}

// ---------------- K_B: unified GEMM, extended K = 4 sections ----------------
// out[b,h,d,s] = sum_k A'[h,k] B'[s,k] + bias, sections:
//   tri:  A=HH*cvec, B=HS   | s_hs: A=HH, B=T2
//   s_ds: A=bcast(cvec2), B=TZ | s_hd: A=HH (tile reuse), B=bcast(cvec3)
// grid (192, 4, 4): x=d, y=(hb<<1)|sb, z=b. 576 thr = 9 waves (3h x 3s strips).
__global__ __launch_bounds__(576) void kB(
    const uint16_t* __restrict__ HH, const uint16_t* __restrict__ HS,
    const uint16_t* __restrict__ dU16, const uint16_t* __restrict__ T216, const uint16_t* __restrict__ TZ16,
    const float* __restrict__ h_dep, const float* __restrict__ partial,
    const float* __restrict__ bias, float* __restrict__ out) {
  __shared__ __align__(16) uint16_t Btile[96 * 128];   // 24 KB
  __shared__ __align__(16) uint16_t Atile[96 * 128];   // 24 KB
  __shared__ __align__(16) uint16_t cvec[NI];    // bf16(w_red * h_dep_d)
  __shared__ __align__(16) uint16_t cvec2[NI];   // bf16(h_dep_d)
  __shared__ __align__(16) uint16_t cvec3[NI];   // dU16 row d, de-swizzled
  const int d = blockIdx.x, hb = blockIdx.y >> 1, sb = blockIdx.y & 1, b = blockIdx.z;
  const int tid = threadIdx.x;
  const int lane = tid & 63, w = tid >> 6;
  const int wh = w / 3, ws = w % 3;
  const int l31 = lane & 31, l5 = lane >> 5;

  // prologue
  if (tid < NI) {
    const float hd = h_dep[(b * SS + d) * NI + tid];
    float wr = 0.f;
    #pragma unroll
    for (int q = 0; q < 8; ++q) wr += partial[8 * tid + q];
    cvec[tid] = f2bf(wr * hd);
    cvec2[tid] = f2bf(hd);
  } else if (tid < NI + 32) {
    const int ck = tid - NI;   // logical chunk c at storage pos c^(d&15)
    ((uint4*)cvec3)[ck] = *(const uint4*)(dU16 + (size_t)(b * SS + d) * NI + ((ck ^ (d & 15)) << 3));
  }
  __syncthreads();

  const int arow = wh * 32 + l31, abyte = arow * 256, amask = arow & 15;
  const int brow = ws * 32 + l31, bbyte = brow * 256, bmask = brow & 15;
  f32x16 acc = {};

  #define STAGE_A_MUL(kbase)                                                          \
    _Pragma("unroll")                                                                 \
    for (int i = 0; i < 3; ++i) {                                                     \
      const int slot = i * 576 + tid;                                                 \
      if (slot < 1536) {                                                              \
        const int row = slot >> 4, kc = slot & 15;                                    \
        const int lcl = kc ^ (row & 15);                                              \
        const uint4 cv4 = *(const uint4*)(cvec + (kbase) + lcl * 8);                  \
        const uint4 hh4 = *(const uint4*)(HH + ((size_t)(b * SS + hb * 96 + row) << 8) + (kbase) + kc * 8); \
        uint4 a4;                                                                     \
        a4.x = bfmul2(hh4.x, cv4.x); a4.y = bfmul2(hh4.y, cv4.y);                     \
        a4.z = bfmul2(hh4.z, cv4.z); a4.w = bfmul2(hh4.w, cv4.w);                     \
        *(uint4*)((char*)Atile + (size_t)slot * 16) = a4;                             \
      }                                                                               \
    }

  #define STAGE_A_COPY(kbase)                                                         \
    _Pragma("unroll")                                                                 \
    for (int i = 0; i < 3; ++i) {                                                     \
      const int slot = i * 576 + tid;                                                 \
      if (slot < 1536) {                                                              \
        const int row = slot >> 4;                                                    \
        const uint16_t* src = HH + ((size_t)(b * SS + hb * 96 + row) << 8) + (kbase) + (slot & 15) * 8; \
        __builtin_amdgcn_global_load_lds((const __attribute__((address_space(1))) void*)src, \
            (__attribute__((address_space(3))) void*)(Atile + (size_t)slot * 8), 16, 0, 0); \
      }                                                                               \
    }

  #define STAGE_B(S, kbase)                                                           \
    _Pragma("unroll")                                                                 \
    for (int i = 0; i < 3; ++i) {                                                     \
      const int slot = i * 576 + tid;                                                 \
      if (slot < 1536) {                                                              \
        const int row = slot >> 4;                                                    \
        const uint16_t* src = (S) + ((size_t)(b * SS + sb * 96 + row) << 8) + (kbase) + (slot & 15) * 8; \
        __builtin_amdgcn_global_load_lds((const __attribute__((address_space(1))) void*)src, \
            (__attribute__((address_space(3))) void*)(Btile + (size_t)slot * 8), 16, 0, 0); \
      }                                                                               \
    }

  #define MM()                                                                        \
    _Pragma("unroll")                                                                 \
    for (int ks = 0; ks < 8; ++ks) {                                                  \
      const int sl = ks * 2 + l5;                                                     \
      bf16x8 af = *reinterpret_cast<const bf16x8*>((const char*)Atile + abyte + ((sl ^ amask) << 4)); \
      bf16x8 bf = *reinterpret_cast<const bf16x8*>((const char*)Btile + bbyte + ((sl ^ bmask) << 4)); \
      acc = __builtin_amdgcn_mfma_f32_32x32x16_bf16(af, bf, acc, 0, 0, 0);            \
    }

  #define MM_BBCAST(koff)                                                             \
    _Pragma("unroll")                                                                 \
    for (int ks = 0; ks < 8; ++ks) {                                                  \
      const int sl = ks * 2 + l5;                                                     \
      bf16x8 af = *reinterpret_cast<const bf16x8*>((const char*)Atile + abyte + ((sl ^ amask) << 4)); \
      bf16x8 bf = *reinterpret_cast<const bf16x8*>(cvec3 + (koff) + sl * 8);          \
      acc = __builtin_amdgcn_mfma_f32_32x32x16_bf16(af, bf, acc, 0, 0, 0);            \
    }

  #define MM_ABCAST(koff)                                                             \
    _Pragma("unroll")                                                                 \
    for (int ks = 0; ks < 8; ++ks) {                                                  \
      const int sl = ks * 2 + l5;                                                     \
      bf16x8 af = *reinterpret_cast<const bf16x8*>(cvec2 + (koff) + sl * 8);          \
      bf16x8 bf = *reinterpret_cast<const bf16x8*>((const char*)Btile + bbyte + ((sl ^ bmask) << 4)); \
      acc = __builtin_amdgcn_mfma_f32_32x32x16_bf16(af, bf, acc, 0, 0, 0);            \
    }

  // P0: tri h0
  STAGE_A_MUL(0); STAGE_B(HS, 0); __syncthreads();
  MM(); __syncthreads();
  // P1: tri h1
  STAGE_A_MUL(128); STAGE_B(HS, 128); __syncthreads();
  MM(); __syncthreads();
  // P2: s_hs h0 + s_hd h0 (Atile = HH h0 shared)
  STAGE_A_COPY(0); STAGE_B(T216, 0); __syncthreads();
  MM(); MM_BBCAST(0); __syncthreads();
  // P3: s_hs h1 + s_hd h1
  STAGE_A_COPY(128); STAGE_B(T216, 128); __syncthreads();
  MM(); MM_BBCAST(128); __syncthreads();
  // P4: s_ds h0 (A = bcast cvec2)
  STAGE_B(TZ16, 0); __syncthreads();
  MM_ABCAST(0); __syncthreads();
  // P5: s_ds h1
  STAGE_B(TZ16, 128); __syncthreads();
  MM_ABCAST(128);

  // epilogue: + bias, pure stores
  const float bias0 = bias[0];
  const int s = sb * 96 + ws * 32 + l31;
  #pragma unroll
  for (int r = 0; r < 16; ++r) {
    const int h = hb * 96 + wh * 32 + (r & 3) + 8 * (r >> 2) + 4 * l5;
    out[((size_t)(b * SS + h) * SS + d) * SS + s] = acc[r] + bias0;
  }
  #undef STAGE_A_MUL
  #undef STAGE_A_COPY
  #undef STAGE_B
  #undef MM
  #undef MM_BBCAST
  #undef MM_ABCAST
}

extern "C" void kernel_launch(void* const* d_in, const int* in_sizes, int n_in,
                              void* d_out, int out_size, void* d_ws, size_t ws_size,
                              hipStream_t stream) {
  const float* h_head = (const float*)d_in[0];
  const float* h_dep  = (const float*)d_in[1];
  const float* h_sib  = (const float*)d_in[2];
  const float* W_tri  = (const float*)d_in[3];
  const float* U_hd   = (const float*)d_in[4];
  const float* V_hs   = (const float*)d_in[5];
  const float* Z_ds   = (const float*)d_in[6];
  const float* bias   = (const float*)d_in[7];
  float* out = (float*)d_out;

  float* ws = (float*)d_ws;
  float* partial = ws;          ws += 2048;
  uint16_t* HH   = (uint16_t*)ws;
  uint16_t* HS   = HH + NB * SS * NI;
  uint16_t* dU16 = HS + NB * SS * NI;
  uint16_t* T216 = dU16 + NB * SS * NI;
  uint16_t* TZ16 = T216 + NB * SS * NI;

  kA<<<2168, 256, 0, stream>>>(W_tri, h_head, h_dep, h_sib, U_hd, V_hs, Z_ds,
                               partial, HH, HS, dU16, T216, TZ16);
  kB<<<dim3(SS, 4, NB), 576, 0, stream>>>(HH, HS, dU16, T216, TZ16,
                                          h_dep, partial, bias, out);
}

// Round 16
// 73.597 us; speedup vs baseline: 1.6118x; 1.6118x over previous
//
#include <hip/hip_runtime.h>
#include <stdint.h>

#define NB 4
#define SS 192
#define NI 256

typedef __attribute__((ext_vector_type(8))) short bf16x8;
typedef __attribute__((ext_vector_type(16))) float f32x16;

__device__ __forceinline__ uint16_t f2bf(float f) {
  union { float f; uint32_t u; } v; v.f = f;
  return (uint16_t)((v.u + 0x7FFFu + ((v.u >> 16) & 1u)) >> 16);
}

__device__ __forceinline__ uint4 pack8(const float4 a, const float4 b) {
  uint4 r;
  r.x = (uint32_t)f2bf(a.x) | ((uint32_t)f2bf(a.y) << 16);
  r.y = (uint32_t)f2bf(a.z) | ((uint32_t)f2bf(a.w) << 16);
  r.z = (uint32_t)f2bf(b.x) | ((uint32_t)f2bf(b.y) << 16);
  r.w = (uint32_t)f2bf(b.z) | ((uint32_t)f2bf(b.w) << 16);
  return r;
}

__device__ __forceinline__ uint32_t bfmul2(uint32_t x, uint32_t y) {
  union { float f; uint32_t u; } xa, xb, ya, yb, r0, r1;
  xa.u = x << 16;        ya.u = y << 16;
  xb.u = x & 0xFFFF0000u; yb.u = y & 0xFFFF0000u;
  r0.f = xa.f * ya.f;
  r1.f = xb.f * yb.f;
  uint32_t lo = (r0.u + 0x7FFFu + ((r0.u >> 16) & 1u)) >> 16;
  uint32_t hi = (r1.u + 0x7FFFu + ((r1.u >> 16) & 1u)) >> 16;
  return lo | (hi << 16);
}

// Canonical bf16 storage: row-major, 8-elem chunk c stored at position c ^ (row&15).
// partial[] contract: 2048 chunks of 8192 floats; w_red[i] = sum(partial[8i..8i+7]).

// ---------------- K_A: s1-blocks (0..23) + HH/HD/HS converts (24..119) + W partials (120..2167) ----------------
__global__ __launch_bounds__(256) void kA(
    const float* __restrict__ W,
    const float* __restrict__ h_head, const float* __restrict__ h_dep, const float* __restrict__ h_sib,
    const float* __restrict__ U, const float* __restrict__ V, const float* __restrict__ Z,
    float* __restrict__ partial,
    uint16_t* __restrict__ HH, uint16_t* __restrict__ HD, uint16_t* __restrict__ HS,
    uint16_t* __restrict__ dU16, uint16_t* __restrict__ T216, uint16_t* __restrict__ TZ16) {
  const int bi = blockIdx.x, tid = threadIdx.x;

  if (bi >= 120) {
    // ---- W chunk: sum 8192 consecutive floats ----
    __shared__ float red[4];
    const int c = bi - 120;
    const float4* pw = (const float4*)(W + (size_t)c * 8192);
    float4 a = {0.f, 0.f, 0.f, 0.f};
    #pragma unroll
    for (int it = 0; it < 8; ++it) {
      const float4 v = pw[it * 256 + tid];
      a.x += v.x; a.y += v.y; a.z += v.z; a.w += v.w;
    }
    float s = (a.x + a.y) + (a.z + a.w);
    for (int off = 32; off > 0; off >>= 1) s += __shfl_down(s, off, 64);
    if ((tid & 63) == 0) red[tid >> 6] = s;
    __syncthreads();
    if (tid == 0) partial[c] = red[0] + red[1] + red[2] + red[3];
    return;
  }
  if (bi >= 24) {
    // ---- converts: canonical swizzled bf16 (HH, HD, HS) ----
    const int rl = tid >> 5, c8 = tid & 31;
    const int g = (bi - 24) * 8 + rl;              // 0..767
    const int dst = g * 32 + (c8 ^ (g & 15));
    const int srci = g * 64 + c8 * 2;
    { const float4 x = ((const float4*)h_head)[srci], y = ((const float4*)h_head)[srci + 1];
      ((uint4*)HH)[dst] = pack8(x, y); }
    { const float4 x = ((const float4*)h_dep)[srci], y = ((const float4*)h_dep)[srci + 1];
      ((uint4*)HD)[dst] = pack8(x, y); }
    { const float4 x = ((const float4*)h_sib)[srci], y = ((const float4*)h_sib)[srci + 1];
      ((uint4*)HS)[dst] = pack8(x, y); }
    return;
  }

  // ---- s1 block: dU/T2/TZ = A(192xK) x B(U/V/Z rows)^T, self-converting staging ----
  {
    __shared__ __align__(16) uint16_t Ah[192 * 128];   // 48 KB
    __shared__ __align__(16) uint16_t Bh[128 * 128];   // 32 KB
    const int which = bi >> 3, rem = bi & 7;
    const int b = rem >> 1, nt = rem & 1;
    const float* As = (which == 0) ? h_dep : h_sib;
    const float* Bs = (which == 0) ? U : (which == 1) ? V : Z;
    uint16_t* Os = (which == 0) ? dU16 : (which == 1) ? T216 : TZ16;
    const int lane = tid & 63, w = tid >> 6;
    const int l31 = lane & 31, l5 = lane >> 5;
    const int N0 = nt * 128;
    f32x16 acc[6] = {};

    #pragma unroll
    for (int kh = 0; kh < 2; ++kh) {
      const int kbase = kh * 128;
      if (kh) __syncthreads();
      #pragma unroll
      for (int i = 0; i < 12; ++i) {
        const int slot = i * 256 + tid;
        const int row = slot >> 4, ck = slot & 15;
        const float* sp = As + (size_t)(b * SS + row) * NI + kbase + ck * 8;
        const float4 x = *(const float4*)sp, y = *(const float4*)(sp + 4);
        *(uint4*)((char*)Ah + row * 256 + ((ck ^ (row & 15)) << 4)) = pack8(x, y);
      }
      #pragma unroll
      for (int i = 0; i < 8; ++i) {
        const int slot = i * 256 + tid;
        const int row = slot >> 4, ck = slot & 15;
        const float* sp = Bs + (size_t)(N0 + row) * NI + kbase + ck * 8;
        const float4 x = *(const float4*)sp, y = *(const float4*)(sp + 4);
        *(uint4*)((char*)Bh + row * 256 + ((ck ^ (row & 15)) << 4)) = pack8(x, y);
      }
      __syncthreads();
      const int brow = w * 32 + l31;
      const int bbyte = brow * 256;
      const int bmask = brow & 15;
      #pragma unroll
      for (int ks = 0; ks < 8; ++ks) {
        const int sl = ks * 2 + l5;
        bf16x8 bf = *reinterpret_cast<const bf16x8*>((const char*)Bh + bbyte + ((sl ^ bmask) << 4));
        #pragma unroll
        for (int mt = 0; mt < 6; ++mt) {
          const int ar = mt * 32 + l31;
          bf16x8 af = *reinterpret_cast<const bf16x8*>((const char*)Ah + ar * 256 + ((sl ^ (ar & 15)) << 4));
          acc[mt] = __builtin_amdgcn_mfma_f32_32x32x16_bf16(af, bf, acc[mt], 0, 0, 0);
        }
      }
    }
    const int n = N0 + w * 32 + l31;
    const int nck = n >> 3, npos = n & 7;
    #pragma unroll
    for (int mt = 0; mt < 6; ++mt) {
      #pragma unroll
      for (int r = 0; r < 16; ++r) {
        const int m = mt * 32 + (r & 3) + 8 * (r >> 2) + 4 * l5;
        Os[(size_t)(b * SS + m) * NI + ((nck ^ (m & 15)) << 3) + npos] = f2bf(acc[mt][r]);
      }
    }
  }
}

// ---------------- K2 stage-2: s_hd/s_hs/s_ds (192x192, K=256), MFMA (R14 verbatim) ----------------
__global__ __launch_bounds__(384, 1) void k_s2(
    const uint16_t* __restrict__ HH, const uint16_t* __restrict__ HD,
    const uint16_t* __restrict__ dU16, const uint16_t* __restrict__ T216, const uint16_t* __restrict__ TZ16,
    float* __restrict__ s_hd, float* __restrict__ s_hs, float* __restrict__ s_ds) {
  __shared__ __align__(16) uint16_t Ah[192 * 128];   // 48 KB
  __shared__ __align__(16) uint16_t Bh[192 * 128];   // 48 KB
  const int which = blockIdx.x, b = blockIdx.y;
  const uint16_t* As = (which == 2) ? HD : HH;
  const uint16_t* Bs = (which == 0) ? dU16 : (which == 1) ? T216 : TZ16;
  float* Os = (which == 0) ? s_hd : (which == 1) ? s_hs : s_ds;
  const int tid = threadIdx.x, lane = tid & 63, w = tid >> 6;
  const int l31 = lane & 31, l5 = lane >> 5;
  f32x16 acc[6] = {};

  #pragma unroll
  for (int kh = 0; kh < 2; ++kh) {
    const int kbase = kh * 128;
    if (kh) __syncthreads();
    #pragma unroll
    for (int i = 0; i < 8; ++i) {
      const int slot = i * 384 + tid;
      const int row = slot >> 4, ck = slot & 15;
      const uint16_t* src = As + (size_t)(b * SS + row) * NI + kbase + ck * 8;
      __builtin_amdgcn_global_load_lds((const __attribute__((address_space(1))) void*)src,
          (__attribute__((address_space(3))) void*)(Ah + (size_t)slot * 8), 16, 0, 0);
    }
    #pragma unroll
    for (int i = 0; i < 8; ++i) {
      const int slot = i * 384 + tid;
      const int row = slot >> 4, ck = slot & 15;
      const uint16_t* src = Bs + (size_t)(b * SS + row) * NI + kbase + ck * 8;
      __builtin_amdgcn_global_load_lds((const __attribute__((address_space(1))) void*)src,
          (__attribute__((address_space(3))) void*)(Bh + (size_t)slot * 8), 16, 0, 0);
    }
    __syncthreads();
    const int brow = w * 32 + l31;
    const int bbyte = brow * 256;
    const int bmask = brow & 15;
    #pragma unroll
    for (int ks = 0; ks < 8; ++ks) {
      const int sl = ks * 2 + l5;
      bf16x8 bf = *reinterpret_cast<const bf16x8*>((const char*)Bh + bbyte + ((sl ^ bmask) << 4));
      #pragma unroll
      for (int mt = 0; mt < 6; ++mt) {
        const int ar = mt * 32 + l31;
        bf16x8 af = *reinterpret_cast<const bf16x8*>((const char*)Ah + ar * 256 + ((sl ^ (ar & 15)) << 4));
        acc[mt] = __builtin_amdgcn_mfma_f32_32x32x16_bf16(af, bf, acc[mt], 0, 0, 0);
      }
    }
  }
  const int n = w * 32 + l31;
  #pragma unroll
  for (int mt = 0; mt < 6; ++mt) {
    #pragma unroll
    for (int r = 0; r < 16; ++r) {
      const int m = mt * 32 + (r & 3) + 8 * (r >> 2) + 4 * l5;
      Os[(size_t)(b * SS + m) * SS + n] = acc[mt][r];
    }
  }
}

// ---------------- K3: main GEMM — 96h x 96s blocks, 9 waves (R14 verbatim) ----------------
__global__ __launch_bounds__(576) void k3_big(
    const uint16_t* __restrict__ HH, const uint16_t* __restrict__ HS,
    const float* __restrict__ h_dep, const float* __restrict__ partial,
    const float* __restrict__ s_hd, const float* __restrict__ s_hs,
    const float* __restrict__ s_ds,
    const float* __restrict__ bias, float* __restrict__ out) {
  __shared__ __align__(16) uint16_t Btile[96 * 128];   // 24 KB
  __shared__ __align__(16) uint16_t Atile[96 * 128];   // 24 KB
  __shared__ uint16_t cvec[NI];
  const int d = blockIdx.x, hb = blockIdx.y >> 1, sb = blockIdx.y & 1, b = blockIdx.z;
  const int tid = threadIdx.x;
  const int lane = tid & 63, w = tid >> 6;
  const int wh = w / 3, ws = w % 3;
  const int l31 = lane & 31, l5 = lane >> 5;

  if (tid < NI) {
    float wr = 0.f;
    #pragma unroll
    for (int q = 0; q < 8; ++q) wr += partial[8 * tid + q];
    cvec[tid] = f2bf(wr * h_dep[(b * SS + d) * NI + tid]);
  }
  __syncthreads();

  f32x16 acc = {};

  #pragma unroll
  for (int half = 0; half < 2; ++half) {
    const int kbase = half * 128;
    if (half) __syncthreads();
    #pragma unroll
    for (int i = 0; i < 3; ++i) {
      const int slot = i * 576 + tid;
      if (slot < 1536) {
        const int row = slot >> 4;
        const uint16_t* src = HS + ((size_t)(b * SS + sb * 96 + row) << 8) + kbase + (slot & 15) * 8;
        __builtin_amdgcn_global_load_lds(
            (const __attribute__((address_space(1))) void*)src,
            (__attribute__((address_space(3))) void*)(Btile + (size_t)slot * 8),
            16, 0, 0);
      }
    }
    #pragma unroll
    for (int i = 0; i < 3; ++i) {
      const int slot = i * 576 + tid;
      if (slot < 1536) {
        const int row = slot >> 4;
        const int kc = slot & 15;
        const int lcl = kc ^ (row & 15);
        const uint4 cv4 = *(const uint4*)(cvec + kbase + lcl * 8);
        const uint4 hh4 = *(const uint4*)(HH + ((size_t)(b * SS + hb * 96 + row) << 8) + kbase + kc * 8);
        uint4 a4;
        a4.x = bfmul2(hh4.x, cv4.x);
        a4.y = bfmul2(hh4.y, cv4.y);
        a4.z = bfmul2(hh4.z, cv4.z);
        a4.w = bfmul2(hh4.w, cv4.w);
        *(uint4*)((char*)Atile + (size_t)slot * 16) = a4;
      }
    }
    __syncthreads();
    const int arow = wh * 32 + l31;
    const int abyte = arow * 256;
    const int amask = arow & 15;
    const int brow = ws * 32 + l31;
    const int bbyte = brow * 256;
    const int bmask = brow & 15;
    #pragma unroll
    for (int ks = 0; ks < 8; ++ks) {
      const int sl = ks * 2 + l5;
      bf16x8 af = *reinterpret_cast<const bf16x8*>((const char*)Atile + abyte + ((sl ^ amask) << 4));
      bf16x8 bf = *reinterpret_cast<const bf16x8*>((const char*)Btile + bbyte + ((sl ^ bmask) << 4));
      acc = __builtin_amdgcn_mfma_f32_32x32x16_bf16(af, bf, acc, 0, 0, 0);
    }
  }

  const float bias0 = bias[0];
  const int s = sb * 96 + ws * 32 + l31;
  const float dsv = s_ds[(b * SS + d) * SS + s];
  #pragma unroll
  for (int r = 0; r < 16; ++r) {
    const int h = hb * 96 + wh * 32 + (r & 3) + 8 * (r >> 2) + 4 * l5;
    const float chd = s_hd[(b * SS + h) * SS + d] + bias0;
    const float v = acc[r] + chd + s_hs[(b * SS + h) * SS + s] + dsv;
    out[((size_t)(b * SS + h) * SS + d) * SS + s] = v;
  }
}

extern "C" void kernel_launch(void* const* d_in, const int* in_sizes, int n_in,
                              void* d_out, int out_size, void* d_ws, size_t ws_size,
                              hipStream_t stream) {
  const float* h_head = (const float*)d_in[0];
  const float* h_dep  = (const float*)d_in[1];
  const float* h_sib  = (const float*)d_in[2];
  const float* W_tri  = (const float*)d_in[3];
  const float* U_hd   = (const float*)d_in[4];
  const float* V_hs   = (const float*)d_in[5];
  const float* Z_ds   = (const float*)d_in[6];
  const float* bias   = (const float*)d_in[7];
  float* out = (float*)d_out;

  float* ws = (float*)d_ws;
  float* partial = ws;          ws += 2048;
  float* s_hd    = ws;          ws += NB * SS * SS;
  float* s_hs    = ws;          ws += NB * SS * SS;
  float* s_ds    = ws;          ws += NB * SS * SS;
  uint16_t* HH   = (uint16_t*)ws;
  uint16_t* HD   = HH + NB * SS * NI;
  uint16_t* HS   = HD + NB * SS * NI;
  uint16_t* dU16 = HS + NB * SS * NI;
  uint16_t* T216 = dU16 + NB * SS * NI;
  uint16_t* TZ16 = T216 + NB * SS * NI;

  kA<<<2168, 256, 0, stream>>>(W_tri, h_head, h_dep, h_sib, U_hd, V_hs, Z_ds,
                               partial, HH, HD, HS, dU16, T216, TZ16);
  k_s2<<<dim3(3, NB), 384, 0, stream>>>(HH, HD, dU16, T216, TZ16, s_hd, s_hs, s_ds);
  k3_big<<<dim3(SS, 4, NB), 576, 0, stream>>>(HH, HS, h_dep, partial,
                                              s_hd, s_hs, s_ds, bias, out);
}

// Round 17
// 71.287 us; speedup vs baseline: 1.6640x; 1.0324x over previous
//
#include <hip/hip_runtime.h>
#include <stdint.h>

#define NB 4
#define SS 192
#define NI 256

typedef __attribute__((ext_vector_type(8))) short bf16x8;
typedef __attribute__((ext_vector_type(16))) float f32x16;

__device__ __forceinline__ uint16_t f2bf(float f) {
  union { float f; uint32_t u; } v; v.f = f;
  return (uint16_t)((v.u + 0x7FFFu + ((v.u >> 16) & 1u)) >> 16);
}

__device__ __forceinline__ uint4 pack8(const float4 a, const float4 b) {
  uint4 r;
  r.x = (uint32_t)f2bf(a.x) | ((uint32_t)f2bf(a.y) << 16);
  r.y = (uint32_t)f2bf(a.z) | ((uint32_t)f2bf(a.w) << 16);
  r.z = (uint32_t)f2bf(b.x) | ((uint32_t)f2bf(b.y) << 16);
  r.w = (uint32_t)f2bf(b.z) | ((uint32_t)f2bf(b.w) << 16);
  return r;
}

__device__ __forceinline__ uint32_t bfmul2(uint32_t x, uint32_t y) {
  union { float f; uint32_t u; } xa, xb, ya, yb, r0, r1;
  xa.u = x << 16;        ya.u = y << 16;
  xb.u = x & 0xFFFF0000u; yb.u = y & 0xFFFF0000u;
  r0.f = xa.f * ya.f;
  r1.f = xb.f * yb.f;
  uint32_t lo = (r0.u + 0x7FFFu + ((r0.u >> 16) & 1u)) >> 16;
  uint32_t hi = (r1.u + 0x7FFFu + ((r1.u >> 16) & 1u)) >> 16;
  return lo | (hi << 16);
}

// Canonical bf16 storage: row-major, 8-elem chunk c stored at position c ^ (row&15).
// partial[] contract: 2048 chunks of 8192 floats; w_red[i] = sum(partial[8i..8i+7]).

// ---------------- K_A: s1-blocks (0..23) + HH/HD/HS converts (24..119) + W partials (120..2167) ----------------
__global__ __launch_bounds__(256) void kA(
    const float* __restrict__ W,
    const float* __restrict__ h_head, const float* __restrict__ h_dep, const float* __restrict__ h_sib,
    const float* __restrict__ U, const float* __restrict__ V, const float* __restrict__ Z,
    float* __restrict__ partial,
    uint16_t* __restrict__ HH, uint16_t* __restrict__ HD, uint16_t* __restrict__ HS,
    uint16_t* __restrict__ dU16, uint16_t* __restrict__ T216, uint16_t* __restrict__ TZ16) {
  const int bi = blockIdx.x, tid = threadIdx.x;

  if (bi >= 120) {
    // ---- W chunk: sum 8192 consecutive floats ----
    __shared__ float red[4];
    const int c = bi - 120;
    const float4* pw = (const float4*)(W + (size_t)c * 8192);
    float4 a = {0.f, 0.f, 0.f, 0.f};
    #pragma unroll
    for (int it = 0; it < 8; ++it) {
      const float4 v = pw[it * 256 + tid];
      a.x += v.x; a.y += v.y; a.z += v.z; a.w += v.w;
    }
    float s = (a.x + a.y) + (a.z + a.w);
    for (int off = 32; off > 0; off >>= 1) s += __shfl_down(s, off, 64);
    if ((tid & 63) == 0) red[tid >> 6] = s;
    __syncthreads();
    if (tid == 0) partial[c] = red[0] + red[1] + red[2] + red[3];
    return;
  }
  if (bi >= 24) {
    // ---- converts: canonical swizzled bf16 (HH, HD, HS) ----
    const int rl = tid >> 5, c8 = tid & 31;
    const int g = (bi - 24) * 8 + rl;              // 0..767
    const int dst = g * 32 + (c8 ^ (g & 15));
    const int srci = g * 64 + c8 * 2;
    { const float4 x = ((const float4*)h_head)[srci], y = ((const float4*)h_head)[srci + 1];
      ((uint4*)HH)[dst] = pack8(x, y); }
    { const float4 x = ((const float4*)h_dep)[srci], y = ((const float4*)h_dep)[srci + 1];
      ((uint4*)HD)[dst] = pack8(x, y); }
    { const float4 x = ((const float4*)h_sib)[srci], y = ((const float4*)h_sib)[srci + 1];
      ((uint4*)HS)[dst] = pack8(x, y); }
    return;
  }

  // ---- s1 block: dU/T2/TZ = A(192xK) x B(U/V/Z rows)^T, self-converting staging ----
  {
    __shared__ __align__(16) uint16_t Ah[192 * 128];   // 48 KB
    __shared__ __align__(16) uint16_t Bh[128 * 128];   // 32 KB
    const int which = bi >> 3, rem = bi & 7;
    const int b = rem >> 1, nt = rem & 1;
    const float* As = (which == 0) ? h_dep : h_sib;
    const float* Bs = (which == 0) ? U : (which == 1) ? V : Z;
    uint16_t* Os = (which == 0) ? dU16 : (which == 1) ? T216 : TZ16;
    const int lane = tid & 63, w = tid >> 6;
    const int l31 = lane & 31, l5 = lane >> 5;
    const int N0 = nt * 128;
    f32x16 acc[6] = {};

    #pragma unroll
    for (int kh = 0; kh < 2; ++kh) {
      const int kbase = kh * 128;
      if (kh) __syncthreads();
      #pragma unroll
      for (int i = 0; i < 12; ++i) {
        const int slot = i * 256 + tid;
        const int row = slot >> 4, ck = slot & 15;
        const float* sp = As + (size_t)(b * SS + row) * NI + kbase + ck * 8;
        const float4 x = *(const float4*)sp, y = *(const float4*)(sp + 4);
        *(uint4*)((char*)Ah + row * 256 + ((ck ^ (row & 15)) << 4)) = pack8(x, y);
      }
      #pragma unroll
      for (int i = 0; i < 8; ++i) {
        const int slot = i * 256 + tid;
        const int row = slot >> 4, ck = slot & 15;
        const float* sp = Bs + (size_t)(N0 + row) * NI + kbase + ck * 8;
        const float4 x = *(const float4*)sp, y = *(const float4*)(sp + 4);
        *(uint4*)((char*)Bh + row * 256 + ((ck ^ (row & 15)) << 4)) = pack8(x, y);
      }
      __syncthreads();
      const int brow = w * 32 + l31;
      const int bbyte = brow * 256;
      const int bmask = brow & 15;
      #pragma unroll
      for (int ks = 0; ks < 8; ++ks) {
        const int sl = ks * 2 + l5;
        bf16x8 bf = *reinterpret_cast<const bf16x8*>((const char*)Bh + bbyte + ((sl ^ bmask) << 4));
        #pragma unroll
        for (int mt = 0; mt < 6; ++mt) {
          const int ar = mt * 32 + l31;
          bf16x8 af = *reinterpret_cast<const bf16x8*>((const char*)Ah + ar * 256 + ((sl ^ (ar & 15)) << 4));
          acc[mt] = __builtin_amdgcn_mfma_f32_32x32x16_bf16(af, bf, acc[mt], 0, 0, 0);
        }
      }
    }
    const int n = N0 + w * 32 + l31;
    const int nck = n >> 3, npos = n & 7;
    #pragma unroll
    for (int mt = 0; mt < 6; ++mt) {
      #pragma unroll
      for (int r = 0; r < 16; ++r) {
        const int m = mt * 32 + (r & 3) + 8 * (r >> 2) + 4 * l5;
        Os[(size_t)(b * SS + m) * NI + ((nck ^ (m & 15)) << 3) + npos] = f2bf(acc[mt][r]);
      }
    }
  }
}

// ---------------- K2 stage-2: s_hd/s_hs/s_ds (192x192, K=256), MFMA ----------------
__global__ __launch_bounds__(384, 1) void k_s2(
    const uint16_t* __restrict__ HH, const uint16_t* __restrict__ HD,
    const uint16_t* __restrict__ dU16, const uint16_t* __restrict__ T216, const uint16_t* __restrict__ TZ16,
    float* __restrict__ s_hd, float* __restrict__ s_hs, float* __restrict__ s_ds) {
  __shared__ __align__(16) uint16_t Ah[192 * 128];   // 48 KB
  __shared__ __align__(16) uint16_t Bh[192 * 128];   // 48 KB
  const int which = blockIdx.x, b = blockIdx.y;
  const uint16_t* As = (which == 2) ? HD : HH;
  const uint16_t* Bs = (which == 0) ? dU16 : (which == 1) ? T216 : TZ16;
  float* Os = (which == 0) ? s_hd : (which == 1) ? s_hs : s_ds;
  const int tid = threadIdx.x, lane = tid & 63, w = tid >> 6;
  const int l31 = lane & 31, l5 = lane >> 5;
  f32x16 acc[6] = {};

  #pragma unroll
  for (int kh = 0; kh < 2; ++kh) {
    const int kbase = kh * 128;
    if (kh) __syncthreads();
    #pragma unroll
    for (int i = 0; i < 8; ++i) {
      const int slot = i * 384 + tid;
      const int row = slot >> 4, ck = slot & 15;
      const uint16_t* src = As + (size_t)(b * SS + row) * NI + kbase + ck * 8;
      __builtin_amdgcn_global_load_lds((const __attribute__((address_space(1))) void*)src,
          (__attribute__((address_space(3))) void*)(Ah + (size_t)slot * 8), 16, 0, 0);
    }
    #pragma unroll
    for (int i = 0; i < 8; ++i) {
      const int slot = i * 384 + tid;
      const int row = slot >> 4, ck = slot & 15;
      const uint16_t* src = Bs + (size_t)(b * SS + row) * NI + kbase + ck * 8;
      __builtin_amdgcn_global_load_lds((const __attribute__((address_space(1))) void*)src,
          (__attribute__((address_space(3))) void*)(Bh + (size_t)slot * 8), 16, 0, 0);
    }
    __syncthreads();
    const int brow = w * 32 + l31;
    const int bbyte = brow * 256;
    const int bmask = brow & 15;
    #pragma unroll
    for (int ks = 0; ks < 8; ++ks) {
      const int sl = ks * 2 + l5;
      bf16x8 bf = *reinterpret_cast<const bf16x8*>((const char*)Bh + bbyte + ((sl ^ bmask) << 4));
      #pragma unroll
      for (int mt = 0; mt < 6; ++mt) {
        const int ar = mt * 32 + l31;
        bf16x8 af = *reinterpret_cast<const bf16x8*>((const char*)Ah + ar * 256 + ((sl ^ (ar & 15)) << 4));
        acc[mt] = __builtin_amdgcn_mfma_f32_32x32x16_bf16(af, bf, acc[mt], 0, 0, 0);
      }
    }
  }
  const int n = w * 32 + l31;
  #pragma unroll
  for (int mt = 0; mt < 6; ++mt) {
    #pragma unroll
    for (int r = 0; r < 16; ++r) {
      const int m = mt * 32 + (r & 3) + 8 * (r >> 2) + 4 * l5;
      Os[(size_t)(b * SS + m) * SS + n] = acc[mt][r];
    }
  }
}

// ---------------- K3: main GEMM — 96h x 96s blocks, 9 waves; s_hd column staged in LDS ----------------
__global__ __launch_bounds__(576) void k3_big(
    const uint16_t* __restrict__ HH, const uint16_t* __restrict__ HS,
    const float* __restrict__ h_dep, const float* __restrict__ partial,
    const float* __restrict__ s_hd, const float* __restrict__ s_hs,
    const float* __restrict__ s_ds,
    const float* __restrict__ bias, float* __restrict__ out) {
  __shared__ __align__(16) uint16_t Btile[96 * 128];   // 24 KB
  __shared__ __align__(16) uint16_t Atile[96 * 128];   // 24 KB
  __shared__ uint16_t cvec[NI];
  __shared__ float chd_s[96];                          // s_hd[b, hb*96..+96, d] staged once
  const int d = blockIdx.x, hb = blockIdx.y >> 1, sb = blockIdx.y & 1, b = blockIdx.z;
  const int tid = threadIdx.x;
  const int lane = tid & 63, w = tid >> 6;
  const int wh = w / 3, ws = w % 3;
  const int l31 = lane & 31, l5 = lane >> 5;

  if (tid < NI) {
    float wr = 0.f;
    #pragma unroll
    for (int q = 0; q < 8; ++q) wr += partial[8 * tid + q];
    cvec[tid] = f2bf(wr * h_dep[(b * SS + d) * NI + tid]);
  } else if (tid < NI + 96) {
    const int t = tid - NI;
    chd_s[t] = s_hd[(size_t)(b * SS + hb * 96 + t) * SS + d];
  }
  __syncthreads();

  f32x16 acc = {};

  #pragma unroll
  for (int half = 0; half < 2; ++half) {
    const int kbase = half * 128;
    if (half) __syncthreads();
    #pragma unroll
    for (int i = 0; i < 3; ++i) {
      const int slot = i * 576 + tid;
      if (slot < 1536) {
        const int row = slot >> 4;
        const uint16_t* src = HS + ((size_t)(b * SS + sb * 96 + row) << 8) + kbase + (slot & 15) * 8;
        __builtin_amdgcn_global_load_lds(
            (const __attribute__((address_space(1))) void*)src,
            (__attribute__((address_space(3))) void*)(Btile + (size_t)slot * 8),
            16, 0, 0);
      }
    }
    #pragma unroll
    for (int i = 0; i < 3; ++i) {
      const int slot = i * 576 + tid;
      if (slot < 1536) {
        const int row = slot >> 4;
        const int kc = slot & 15;
        const int lcl = kc ^ (row & 15);
        const uint4 cv4 = *(const uint4*)(cvec + kbase + lcl * 8);
        const uint4 hh4 = *(const uint4*)(HH + ((size_t)(b * SS + hb * 96 + row) << 8) + kbase + kc * 8);
        uint4 a4;
        a4.x = bfmul2(hh4.x, cv4.x);
        a4.y = bfmul2(hh4.y, cv4.y);
        a4.z = bfmul2(hh4.z, cv4.z);
        a4.w = bfmul2(hh4.w, cv4.w);
        *(uint4*)((char*)Atile + (size_t)slot * 16) = a4;
      }
    }
    __syncthreads();
    const int arow = wh * 32 + l31;
    const int abyte = arow * 256;
    const int amask = arow & 15;
    const int brow = ws * 32 + l31;
    const int bbyte = brow * 256;
    const int bmask = brow & 15;
    #pragma unroll
    for (int ks = 0; ks < 8; ++ks) {
      const int sl = ks * 2 + l5;
      bf16x8 af = *reinterpret_cast<const bf16x8*>((const char*)Atile + abyte + ((sl ^ amask) << 4));
      bf16x8 bf = *reinterpret_cast<const bf16x8*>((const char*)Btile + bbyte + ((sl ^ bmask) << 4));
      acc = __builtin_amdgcn_mfma_f32_32x32x16_bf16(af, bf, acc, 0, 0, 0);
    }
  }

  const float bias0 = bias[0];
  const int s = sb * 96 + ws * 32 + l31;
  const float dsv = s_ds[(b * SS + d) * SS + s];
  #pragma unroll
  for (int r = 0; r < 16; ++r) {
    const int hl = wh * 32 + (r & 3) + 8 * (r >> 2) + 4 * l5;       // h within this hb block
    const float v = acc[r] + chd_s[hl] + bias0
                  + s_hs[(size_t)(b * SS + hb * 96 + hl) * SS + s] + dsv;
    out[((size_t)(b * SS + hb * 96 + hl) * SS + d) * SS + s] = v;
  }
}

extern "C" void kernel_launch(void* const* d_in, const int* in_sizes, int n_in,
                              void* d_out, int out_size, void* d_ws, size_t ws_size,
                              hipStream_t stream) {
  const float* h_head = (const float*)d_in[0];
  const float* h_dep  = (const float*)d_in[1];
  const float* h_sib  = (const float*)d_in[2];
  const float* W_tri  = (const float*)d_in[3];
  const float* U_hd   = (const float*)d_in[4];
  const float* V_hs   = (const float*)d_in[5];
  const float* Z_ds   = (const float*)d_in[6];
  const float* bias   = (const float*)d_in[7];
  float* out = (float*)d_out;

  float* ws = (float*)d_ws;
  float* partial = ws;          ws += 2048;
  float* s_hd    = ws;          ws += NB * SS * SS;
  float* s_hs    = ws;          ws += NB * SS * SS;
  float* s_ds    = ws;          ws += NB * SS * SS;
  uint16_t* HH   = (uint16_t*)ws;
  uint16_t* HD   = HH + NB * SS * NI;
  uint16_t* HS   = HD + NB * SS * NI;
  uint16_t* dU16 = HS + NB * SS * NI;
  uint16_t* T216 = dU16 + NB * SS * NI;
  uint16_t* TZ16 = T216 + NB * SS * NI;

  kA<<<2168, 256, 0, stream>>>(W_tri, h_head, h_dep, h_sib, U_hd, V_hs, Z_ds,
                               partial, HH, HD, HS, dU16, T216, TZ16);
  k_s2<<<dim3(3, NB), 384, 0, stream>>>(HH, HD, dU16, T216, TZ16, s_hd, s_hs, s_ds);
  k3_big<<<dim3(SS, 4, NB), 576, 0, stream>>>(HH, HS, h_dep, partial,
                                              s_hd, s_hs, s_ds, bias, out);
}